// Round 4
// baseline (156.466 us; speedup 1.0000x reference)
//
#include <hip/hip_runtime.h>

#define FEAT_DIM 8
#define RES 128
#define MAP_NUM 128
#define MAP_OFFSET (RES * RES)

typedef float v2f __attribute__((ext_vector_type(2)));
typedef float v4f __attribute__((ext_vector_type(4)));

// Work decomposition for L2 locality:
//   block = 256 threads = 32 batch x 8 maps (lane: ml = tid&7 fastest)
//   -> each block gathers from an 8-map subtable = 8*16384*32B = 4MB (one XCD L2)
//   XCD swizzle: block g -> XCD g%8 (dispatch round-robin); XCD x owns map
//   groups 2x, 2x+1 (maps 16x..16x+15), walking all 1024 b-chunks of a group
//   before the next -> one ~4MB subtable hot per XCD L2 at a time.
// Stores are NORMAL cached stores: the 40B/thread pattern relies on L2
// write-merging into full 64B lines (nt stores caused partial-line HBM
// writes: WRITE_SIZE 226MB vs 168MB ideal, and big slowdown).
__global__ __launch_bounds__(256) void densemap_fwd(
    const float* __restrict__ inputs,
    const float* __restrict__ emb,
    float* __restrict__ out)
{
    int g = blockIdx.x;
    int x  = g & 7;          // XCD id (by dispatch round-robin)
    int t  = g >> 3;         // 0..2047 per XCD
    int gl = t >> 10;        // which of this XCD's 2 map-groups
    int c  = t & 1023;       // b-chunk within group
    int m0 = ((x << 1) + gl) << 3;   // first map of group (multiple of 8)
    int b0 = c << 5;                 // 32 batch items per block

    int ml = threadIdx.x & 7;
    int bl = threadIdx.x >> 3;
    int m = m0 + ml;
    int b = b0 + bl;
    int idx = b * MAP_NUM + m;       // < 2^22, fits int

    // coalesced (64B full-line) streaming input load
    const v2f* inp2 = reinterpret_cast<const v2f*>(inputs);
    v2f in2 = __builtin_nontemporal_load(inp2 + idx);

    float x0 = in2.x * (float)(RES - 1);
    float x1 = in2.y * (float)(RES - 1);
    int xi0 = (int)x0;               // x >= 0, trunc == floor
    int xi1 = (int)x1;
    float xf0 = x0 - (float)xi0;
    float xf1 = x1 - (float)xi1;

    // corner rows: base, base+1, base+RES, base+RES+1
    size_t base = (size_t)m * MAP_OFFSET + (size_t)xi0 * RES + xi1;

    const v4f* e4 = reinterpret_cast<const v4f*>(emb);
    v4f r00a = e4[2 * base];
    v4f r00b = e4[2 * base + 1];
    v4f r01a = e4[2 * (base + 1)];
    v4f r01b = e4[2 * (base + 1) + 1];
    v4f r10a = e4[2 * (base + RES)];
    v4f r10b = e4[2 * (base + RES) + 1];
    v4f r11a = e4[2 * (base + RES + 1)];
    v4f r11b = e4[2 * (base + RES + 1) + 1];

    float w00 = (1.0f - xf0) * (1.0f - xf1);
    float w01 = (1.0f - xf0) * xf1;
    float w10 = xf0 * (1.0f - xf1);
    float w11 = xf0 * xf1;

    v4f fa = r00a * w00 + r01a * w01 + r10a * w10 + r11a * w11;
    v4f fb = r00b * w00 + r01b * w01 + r10b * w10 + r11b * w11;

    // 40B per thread, 8B-aligned: 5 x v2f normal stores (L2 merges lines)
    v2f* o2 = reinterpret_cast<v2f*>(out + (size_t)idx * 10);
    v2f s0 = {fa.x, fa.y};
    v2f s1 = {fa.z, fa.w};
    v2f s2 = {fb.x, fb.y};
    v2f s3 = {fb.z, fb.w};
    v2f s4 = {xf0, xf1};
    o2[0] = s0;
    o2[1] = s1;
    o2[2] = s2;
    o2[3] = s3;
    o2[4] = s4;
}

extern "C" void kernel_launch(void* const* d_in, const int* in_sizes, int n_in,
                              void* d_out, int out_size, void* d_ws, size_t ws_size,
                              hipStream_t stream) {
    const float* inputs = (const float*)d_in[0];      // 32768*128*2
    const float* emb    = (const float*)d_in[1];      // 128*16384*8
    float* out          = (float*)d_out;              // 32768*128*10

    // 16 map-groups (8 maps each) x 1024 b-chunks (32 b each) = 16384 blocks
    int grid = 16384;
    densemap_fwd<<<grid, 256, 0, stream>>>(inputs, emb, out);
}

// Round 5
// 136.695 us; speedup vs baseline: 1.1446x; 1.1446x over previous
//
#include <hip/hip_runtime.h>

#define RES 128
#define MAP_NUM 128
#define MAP_OFFSET (RES * RES)

typedef float v2f __attribute__((ext_vector_type(2)));
typedef float v4f __attribute__((ext_vector_type(4)));

// Decomposition (unchanged): block = 256 threads = 32 batch x 8 maps.
// Each block gathers from an 8-map subtable (4MB = one XCD L2); XCD swizzle
// (g%8 -> XCD) walks all 1024 b-chunks of a map-group per XCD before moving on.
//
// NEW: output staged in LDS, then written as full-line nontemporal float4
// stores. This avoids BOTH failure modes seen so far:
//   r3: nt 8B/thread stores -> partial-line HBM writes (WRITE 226MB, RMW)
//   r4: normal stores -> L2 pollution evicts subtable (FETCH 197MB)
// After staging, each 64B output line is covered by 4 consecutive lanes of one
// store instruction -> full-line nt writes, L2 untouched by store data.
__global__ __launch_bounds__(256) void densemap_fwd(
    const float* __restrict__ inputs,
    const float* __restrict__ emb,
    float* __restrict__ out)
{
    __shared__ float lds[32 * 80];   // 32 segments x 80 floats = 10240 B

    int g = blockIdx.x;
    int x  = g & 7;          // XCD id (dispatch round-robin)
    int t  = g >> 3;
    int gl = t >> 10;        // which of this XCD's 2 map-groups
    int c  = t & 1023;       // b-chunk within group
    int m0 = ((x << 1) + gl) << 3;   // first map of group (multiple of 8)
    int b0 = c << 5;                 // 32 batch items per block

    int ml = threadIdx.x & 7;
    int bl = threadIdx.x >> 3;
    int m = m0 + ml;
    int b = b0 + bl;
    int idx = b * MAP_NUM + m;

    // coalesced streaming input load (64B full-line segments)
    const v2f* inp2 = reinterpret_cast<const v2f*>(inputs);
    v2f in2 = __builtin_nontemporal_load(inp2 + idx);

    float x0 = in2.x * (float)(RES - 1);
    float x1 = in2.y * (float)(RES - 1);
    int xi0 = (int)x0;               // x >= 0, trunc == floor
    int xi1 = (int)x1;
    float xf0 = x0 - (float)xi0;
    float xf1 = x1 - (float)xi1;

    // corner rows: base, base+1, base+RES, base+RES+1
    size_t base = (size_t)m * MAP_OFFSET + (size_t)xi0 * RES + xi1;

    const v4f* e4 = reinterpret_cast<const v4f*>(emb);
    v4f r00a = e4[2 * base];
    v4f r00b = e4[2 * base + 1];
    v4f r01a = e4[2 * (base + 1)];
    v4f r01b = e4[2 * (base + 1) + 1];
    v4f r10a = e4[2 * (base + RES)];
    v4f r10b = e4[2 * (base + RES) + 1];
    v4f r11a = e4[2 * (base + RES + 1)];
    v4f r11b = e4[2 * (base + RES + 1) + 1];

    float w00 = (1.0f - xf0) * (1.0f - xf1);
    float w01 = (1.0f - xf0) * xf1;
    float w10 = xf0 * (1.0f - xf1);
    float w11 = xf0 * xf1;

    v4f fa = r00a * w00 + r01a * w01 + r10a * w10 + r11a * w11;
    v4f fb = r00b * w00 + r01b * w01 + r10b * w10 + r11b * w11;

    // stage to LDS: segment bl holds maps m0..m0+7 (80 floats)
    v2f* s2 = reinterpret_cast<v2f*>(lds + bl * 80 + ml * 10);  // even idx -> 8B aligned
    s2[0] = v2f{fa.x, fa.y};
    s2[1] = v2f{fa.z, fa.w};
    s2[2] = v2f{fb.x, fb.y};
    s2[3] = v2f{fb.z, fb.w};
    s2[4] = v2f{xf0, xf1};

    __syncthreads();

    // write out 640 float4 (= 32 segments x 20), full-line nt stores
    const v4f* l4 = reinterpret_cast<const v4f*>(lds);
    float* ob = out + ((size_t)b0 * MAP_NUM + m0) * 10;  // 320B-aligned
    for (int j = threadIdx.x; j < 640; j += 256) {
        int seg = j / 20;            // magic-mul div by const
        int wi  = j - seg * 20;
        v4f val = l4[j];
        float* dst = ob + (size_t)seg * (MAP_NUM * 10) + wi * 4;  // 16B-aligned
        __builtin_nontemporal_store(val, reinterpret_cast<v4f*>(dst));
    }
}

extern "C" void kernel_launch(void* const* d_in, const int* in_sizes, int n_in,
                              void* d_out, int out_size, void* d_ws, size_t ws_size,
                              hipStream_t stream) {
    const float* inputs = (const float*)d_in[0];      // 32768*128*2
    const float* emb    = (const float*)d_in[1];      // 128*16384*8
    float* out          = (float*)d_out;              // 32768*128*10

    // 16 map-groups (8 maps each) x 1024 b-chunks (32 b each) = 16384 blocks
    int grid = 16384;
    densemap_fwd<<<grid, 256, 0, stream>>>(inputs, emb, out);
}